// Round 4
// baseline (447.328 us; speedup 1.0000x reference)
//
#include <hip/hip_runtime.h>

// GatedEncoderLayer: B=16, I=2048, J=1024, K=1024, F=32
// out[row,k] = sum_f [ (sum_j x[row,j]*Wy[j,f]) * Wx[row%I,f] ] * Wz[k,f]
constexpr int kI = 2048;
constexpr int kJ = 1024;
constexpr int kK = 1024;
constexpr int kF = 32;
constexpr int kRows = 16 * 2048;        // 32768

// ---------------------------------------------------------------------------
// Stage 1: t[row,f] = (sum_j x[row,j]*Wy[j,f]) * Wx[row%I,f]
// 512 blocks x 512 threads (2 blocks/CU, 16 waves/CU). 64 rows/block.
// Wy staged in LDS (two 64 KiB chunks, linear copy). Thread = (row, f-quad).
// LDS reads: 8 distinct 16B addrs x 8-lane broadcast -> conflict-free.
// Only x streams from HBM.
// ---------------------------------------------------------------------------
constexpr int kChunkJ = 512;

__global__ __launch_bounds__(512, 4)
void ge_stage1(const float* __restrict__ x,
               const float* __restrict__ Wx,
               const float* __restrict__ Wy,
               float* __restrict__ t)
{
    __shared__ float wy[kChunkJ][kF];                  // 64 KiB

    const int tid  = threadIdx.x;
    const int rloc = tid >> 3;                         // 0..63
    const int f0   = (tid & 7) * 4;                    // 0,4,...,28
    const int row  = blockIdx.x * 64 + rloc;
    const float* __restrict__ xrow = x + (size_t)row * kJ;

    float4 acc = make_float4(0.f, 0.f, 0.f, 0.f);

    for (int c = 0; c < kJ / kChunkJ; ++c) {
        __syncthreads();                               // protect prev chunk readers
        // linear copy: 512*32 floats = 4096 float4 / 512 threads = 8 each
        {
            const float4* src = reinterpret_cast<const float4*>(
                Wy + (size_t)c * kChunkJ * kF);
            float4* dst = reinterpret_cast<float4*>(&wy[0][0]);
#pragma unroll
            for (int p = 0; p < 8; ++p)
                dst[tid + p * 512] = src[tid + p * 512];
        }
        __syncthreads();

        const float* __restrict__ xc = xrow + c * kChunkJ;
#pragma unroll 2
        for (int j = 0; j < kChunkJ; j += 8) {
            const float4 xv0 = *reinterpret_cast<const float4*>(xc + j);
            const float4 xv1 = *reinterpret_cast<const float4*>(xc + j + 4);
            const float xs[8] = {xv0.x, xv0.y, xv0.z, xv0.w,
                                 xv1.x, xv1.y, xv1.z, xv1.w};
#pragma unroll
            for (int u = 0; u < 8; ++u) {
                const float4 w = *reinterpret_cast<const float4*>(&wy[j + u][f0]);
                acc.x = fmaf(xs[u], w.x, acc.x);
                acc.y = fmaf(xs[u], w.y, acc.y);
                acc.z = fmaf(xs[u], w.z, acc.z);
                acc.w = fmaf(xs[u], w.w, acc.w);
            }
        }
    }

    const int i = row & (kI - 1);
    const float4 g = *reinterpret_cast<const float4*>(Wx + (size_t)i * kF + f0);
    acc.x *= g.x; acc.y *= g.y; acc.z *= g.z; acc.w *= g.w;
    *reinterpret_cast<float4*>(t + (size_t)row * kF + f0) = acc;
}

// ---------------------------------------------------------------------------
// Stage 2: out[row,k] = sum_f t[row,f] * Wz[k,f]
// 512 blocks x 512 threads, 64 rows/block. Thread owns 2 k-columns;
// Wz[k0..k0+1][0..31] held in 64 VGPRs (loaded once). t tile (8 KiB) in LDS,
// read as wave-uniform broadcasts. float2 stores, lane-consecutive.
// ---------------------------------------------------------------------------
__global__ __launch_bounds__(512, 4)
void ge_stage2(const float* __restrict__ t,
               const float* __restrict__ Wz,
               float* __restrict__ out)
{
    __shared__ float t2[64][kF];                       // 8 KiB

    const int tid = threadIdx.x;
    const int rowBase = blockIdx.x * 64;

    // stage t tile: 64*32 floats = 2048 float4 / 512 threads = 4 each (linear)
    {
        const float4* src = reinterpret_cast<const float4*>(t + (size_t)rowBase * kF);
        float4* dst = reinterpret_cast<float4*>(&t2[0][0]);
#pragma unroll
        for (int p = 0; p < 4; ++p)
            dst[tid + p * 512] = src[tid + p * 512];
    }

    // Wz for my 2 k-columns -> 16 float4 (64 VGPR), loaded once from L2
    const int k0 = tid * 2;
    float4 wa[8], wb[8];
#pragma unroll
    for (int q = 0; q < 8; ++q) {
        wa[q] = *reinterpret_cast<const float4*>(Wz + (size_t)k0 * kF + q * 4);
        wb[q] = *reinterpret_cast<const float4*>(Wz + (size_t)(k0 + 1) * kF + q * 4);
    }
    __syncthreads();

    float* __restrict__ orow = out + (size_t)rowBase * kK + k0;

    for (int r = 0; r < 64; ++r) {
        float4 tr[8];
#pragma unroll
        for (int q = 0; q < 8; ++q)
            tr[q] = *reinterpret_cast<const float4*>(&t2[r][q * 4]);

        float a0 = 0.f, a1 = 0.f, b0 = 0.f, b1 = 0.f;
#pragma unroll
        for (int q = 0; q < 8; q += 2) {
            a0 = fmaf(tr[q].x, wa[q].x, a0);
            a0 = fmaf(tr[q].y, wa[q].y, a0);
            a0 = fmaf(tr[q].z, wa[q].z, a0);
            a0 = fmaf(tr[q].w, wa[q].w, a0);
            a1 = fmaf(tr[q + 1].x, wa[q + 1].x, a1);
            a1 = fmaf(tr[q + 1].y, wa[q + 1].y, a1);
            a1 = fmaf(tr[q + 1].z, wa[q + 1].z, a1);
            a1 = fmaf(tr[q + 1].w, wa[q + 1].w, a1);
            b0 = fmaf(tr[q].x, wb[q].x, b0);
            b0 = fmaf(tr[q].y, wb[q].y, b0);
            b0 = fmaf(tr[q].z, wb[q].z, b0);
            b0 = fmaf(tr[q].w, wb[q].w, b0);
            b1 = fmaf(tr[q + 1].x, wb[q + 1].x, b1);
            b1 = fmaf(tr[q + 1].y, wb[q + 1].y, b1);
            b1 = fmaf(tr[q + 1].z, wb[q + 1].z, b1);
            b1 = fmaf(tr[q + 1].w, wb[q + 1].w, b1);
        }
        float2 o;
        o.x = a0 + a1;
        o.y = b0 + b1;
        *reinterpret_cast<float2*>(orow + (size_t)r * kK) = o;
    }
}

// ---------------------------------------------------------------------------
// Fallback: round-1 fused kernel (proven correct) if ws too small.
// ---------------------------------------------------------------------------
__global__ __launch_bounds__(256, 2)
void gated_encoder_fused(const float* __restrict__ x,
                         const float* __restrict__ Wx,
                         const float* __restrict__ Wy,
                         const float* __restrict__ Wz,
                         float* __restrict__ out)
{
    __shared__ float t2[64][kF + 4];

    const int tid  = threadIdx.x;
    const int lane = tid & 63;
    const int wv   = tid >> 6;

    const int rloc = wv * 16 + (lane >> 2);
    const int row  = blockIdx.x * 64 + rloc;
    const int fg8  = (lane & 3) * 8;

    const float* __restrict__ xrow = x + (size_t)row * kJ;

    float acc[8];
#pragma unroll
    for (int u = 0; u < 8; ++u) acc[u] = 0.0f;

    for (int j = 0; j < kJ; j += 8) {
        const float4 xv0 = *reinterpret_cast<const float4*>(xrow + j);
        const float4 xv1 = *reinterpret_cast<const float4*>(xrow + j + 4);
        const float xs[8] = {xv0.x, xv0.y, xv0.z, xv0.w,
                             xv1.x, xv1.y, xv1.z, xv1.w};
#pragma unroll
        for (int u = 0; u < 8; ++u) {
            const float* wyp = Wy + (size_t)(j + u) * kF + fg8;
            const float4 w0 = *reinterpret_cast<const float4*>(wyp);
            const float4 w1 = *reinterpret_cast<const float4*>(wyp + 4);
            acc[0] = fmaf(xs[u], w0.x, acc[0]);
            acc[1] = fmaf(xs[u], w0.y, acc[1]);
            acc[2] = fmaf(xs[u], w0.z, acc[2]);
            acc[3] = fmaf(xs[u], w0.w, acc[3]);
            acc[4] = fmaf(xs[u], w1.x, acc[4]);
            acc[5] = fmaf(xs[u], w1.y, acc[5]);
            acc[6] = fmaf(xs[u], w1.z, acc[6]);
            acc[7] = fmaf(xs[u], w1.w, acc[7]);
        }
    }

    const int i = row & (kI - 1);
    const float* wxp = Wx + (size_t)i * kF + fg8;
    const float4 g0 = *reinterpret_cast<const float4*>(wxp);
    const float4 g1 = *reinterpret_cast<const float4*>(wxp + 4);
    float4 r0, r1;
    r0.x = acc[0] * g0.x;  r0.y = acc[1] * g0.y;
    r0.z = acc[2] * g0.z;  r0.w = acc[3] * g0.w;
    r1.x = acc[4] * g1.x;  r1.y = acc[5] * g1.y;
    r1.z = acc[6] * g1.z;  r1.w = acc[7] * g1.w;
    *reinterpret_cast<float4*>(&t2[rloc][fg8])     = r0;
    *reinterpret_cast<float4*>(&t2[rloc][fg8 + 4]) = r1;

    __syncthreads();

    const size_t outBase = (size_t)blockIdx.x * 64 * kK;

#pragma unroll
    for (int pass = 0; pass < 2; ++pass) {
        const int k1 = pass * 512 + tid;
        const int k2 = k1 + 256;
        const float* wz1 = Wz + (size_t)k1 * kF;
        const float* wz2 = Wz + (size_t)k2 * kF;
        float4 z1[8], z2[8];
#pragma unroll
        for (int m = 0; m < 8; ++m) {
            z1[m] = *reinterpret_cast<const float4*>(wz1 + 4 * m);
            z2[m] = *reinterpret_cast<const float4*>(wz2 + 4 * m);
        }
        for (int r = 0; r < 64; ++r) {
            float4 a1 = {0.f, 0.f, 0.f, 0.f};
            float4 a2 = {0.f, 0.f, 0.f, 0.f};
#pragma unroll
            for (int m = 0; m < 8; ++m) {
                const float4 tv = *reinterpret_cast<const float4*>(&t2[r][4 * m]);
                a1.x = fmaf(tv.x, z1[m].x, a1.x);
                a1.y = fmaf(tv.y, z1[m].y, a1.y);
                a1.z = fmaf(tv.z, z1[m].z, a1.z);
                a1.w = fmaf(tv.w, z1[m].w, a1.w);
                a2.x = fmaf(tv.x, z2[m].x, a2.x);
                a2.y = fmaf(tv.y, z2[m].y, a2.y);
                a2.z = fmaf(tv.z, z2[m].z, a2.z);
                a2.w = fmaf(tv.w, z2[m].w, a2.w);
            }
            out[outBase + (size_t)r * kK + k1] = (a1.x + a1.y) + (a1.z + a1.w);
            out[outBase + (size_t)r * kK + k2] = (a2.x + a2.y) + (a2.z + a2.w);
        }
    }
}

extern "C" void kernel_launch(void* const* d_in, const int* in_sizes, int n_in,
                              void* d_out, int out_size, void* d_ws, size_t ws_size,
                              hipStream_t stream) {
    const float* x  = (const float*)d_in[0];   // (B, I, J)
    const float* Wx = (const float*)d_in[1];   // (I, F)
    const float* Wy = (const float*)d_in[2];   // (J, F)
    const float* Wz = (const float*)d_in[3];   // (K, F)
    float* out = (float*)d_out;                // (B, I, K) f32

    const size_t tBytes = (size_t)kRows * kF * sizeof(float);   // 4 MiB

    if (ws_size >= tBytes && d_ws != nullptr) {
        float* t = (float*)d_ws;
        ge_stage1<<<dim3(kRows / 64), 512, 0, stream>>>(x, Wx, Wy, t);
        ge_stage2<<<dim3(kRows / 64), 512, 0, stream>>>(t, Wz, out);
    } else {
        gated_encoder_fused<<<dim3(kRows / 64), 256, 0, stream>>>(x, Wx, Wy, Wz, out);
    }
}

// Round 5
// 104.809 us; speedup vs baseline: 4.2680x; 4.2680x over previous
//
#include <hip/hip_runtime.h>

// GatedEncoderLayer: B=16, I=2048, J=1024, K=1024, F=32
// out[row,k] = sum_f [ (sum_j x[row,j]*Wy[j,f]) * Wx[row%I,f] ] * Wz[k,f]
constexpr int kI = 2048;
constexpr int kJ = 1024;
constexpr int kK = 1024;
constexpr int kF = 32;
constexpr int kRows = 16 * 2048;        // 32768

// ---------------------------------------------------------------------------
// Stage 1: t[row,f] = (sum_j x[row,j]*Wy[j,f]) * Wx[row%I,f]
// 512 blocks x 512 threads. 64 rows/block. Wy staged in LDS (two 64 KiB
// chunks). Thread = (row, f-quad). LDS reads: 8 distinct addrs x 8-lane
// broadcast -> conflict-free. Only x streams from HBM.  (~50 us measured)
// ---------------------------------------------------------------------------
constexpr int kChunkJ = 512;

__global__ __launch_bounds__(512, 4)
void ge_stage1(const float* __restrict__ x,
               const float* __restrict__ Wx,
               const float* __restrict__ Wy,
               float* __restrict__ t)
{
    __shared__ float wy[kChunkJ][kF];                  // 64 KiB

    const int tid  = threadIdx.x;
    const int rloc = tid >> 3;                         // 0..63
    const int f0   = (tid & 7) * 4;                    // 0,4,...,28
    const int row  = blockIdx.x * 64 + rloc;
    const float* __restrict__ xrow = x + (size_t)row * kJ;

    float4 acc = make_float4(0.f, 0.f, 0.f, 0.f);

    for (int c = 0; c < kJ / kChunkJ; ++c) {
        __syncthreads();                               // protect prev chunk readers
        {
            const float4* src = reinterpret_cast<const float4*>(
                Wy + (size_t)c * kChunkJ * kF);
            float4* dst = reinterpret_cast<float4*>(&wy[0][0]);
#pragma unroll
            for (int p = 0; p < 8; ++p)
                dst[tid + p * 512] = src[tid + p * 512];
        }
        __syncthreads();

        const float* __restrict__ xc = xrow + c * kChunkJ;
#pragma unroll 2
        for (int j = 0; j < kChunkJ; j += 8) {
            const float4 xv0 = *reinterpret_cast<const float4*>(xc + j);
            const float4 xv1 = *reinterpret_cast<const float4*>(xc + j + 4);
            const float xs[8] = {xv0.x, xv0.y, xv0.z, xv0.w,
                                 xv1.x, xv1.y, xv1.z, xv1.w};
#pragma unroll
            for (int u = 0; u < 8; ++u) {
                const float4 w = *reinterpret_cast<const float4*>(&wy[j + u][f0]);
                acc.x = fmaf(xs[u], w.x, acc.x);
                acc.y = fmaf(xs[u], w.y, acc.y);
                acc.z = fmaf(xs[u], w.z, acc.z);
                acc.w = fmaf(xs[u], w.w, acc.w);
            }
        }
    }

    const int i = row & (kI - 1);
    const float4 g = *reinterpret_cast<const float4*>(Wx + (size_t)i * kF + f0);
    acc.x *= g.x; acc.y *= g.y; acc.z *= g.z; acc.w *= g.w;
    *reinterpret_cast<float4*>(t + (size_t)row * kF + f0) = acc;
}

// ---------------------------------------------------------------------------
// Stage 2: out[row,k] = sum_f t[row,f] * Wz[k,f]
// 512 blocks x 512 threads, 64 rows/block. Thread owns 2 k-columns with
// Wz in 64 VGPRs. launch_bounds(512,2): VGPR cap 256 — the (512,4) variant
// capped at 64 VGPR and spilled wa/wb to scratch (FETCH 1.25 GB, round 4).
// ---------------------------------------------------------------------------
__global__ __launch_bounds__(512, 2)
void ge_stage2(const float* __restrict__ t,
               const float* __restrict__ Wz,
               float* __restrict__ out)
{
    __shared__ float t2[64][kF];                       // 8 KiB = 512 float4

    const int tid = threadIdx.x;
    const int rowBase = blockIdx.x * 64;

    // stage t tile: exactly one float4 per thread (round-4 bug: copied 4x OOB)
    reinterpret_cast<float4*>(&t2[0][0])[tid] =
        reinterpret_cast<const float4*>(t + (size_t)rowBase * kF)[tid];

    // Wz for my 2 k-columns -> 16 float4 (64 VGPR), loaded once
    const int k0 = tid * 2;
    float4 wa[8], wb[8];
#pragma unroll
    for (int q = 0; q < 8; ++q) {
        wa[q] = *reinterpret_cast<const float4*>(Wz + (size_t)k0 * kF + q * 4);
        wb[q] = *reinterpret_cast<const float4*>(Wz + (size_t)(k0 + 1) * kF + q * 4);
    }
    __syncthreads();

    float* __restrict__ orow = out + (size_t)rowBase * kK + k0;

    for (int r = 0; r < 64; ++r) {
        float4 tr[8];
#pragma unroll
        for (int q = 0; q < 8; ++q)
            tr[q] = *reinterpret_cast<const float4*>(&t2[r][q * 4]);

        float a0 = 0.f, a1 = 0.f, b0 = 0.f, b1 = 0.f;
#pragma unroll
        for (int q = 0; q < 8; q += 2) {
            a0 = fmaf(tr[q].x, wa[q].x, a0);
            a0 = fmaf(tr[q].y, wa[q].y, a0);
            a0 = fmaf(tr[q].z, wa[q].z, a0);
            a0 = fmaf(tr[q].w, wa[q].w, a0);
            a1 = fmaf(tr[q + 1].x, wa[q + 1].x, a1);
            a1 = fmaf(tr[q + 1].y, wa[q + 1].y, a1);
            a1 = fmaf(tr[q + 1].z, wa[q + 1].z, a1);
            a1 = fmaf(tr[q + 1].w, wa[q + 1].w, a1);
            b0 = fmaf(tr[q].x, wb[q].x, b0);
            b0 = fmaf(tr[q].y, wb[q].y, b0);
            b0 = fmaf(tr[q].z, wb[q].z, b0);
            b0 = fmaf(tr[q].w, wb[q].w, b0);
            b1 = fmaf(tr[q + 1].x, wb[q + 1].x, b1);
            b1 = fmaf(tr[q + 1].y, wb[q + 1].y, b1);
            b1 = fmaf(tr[q + 1].z, wb[q + 1].z, b1);
            b1 = fmaf(tr[q + 1].w, wb[q + 1].w, b1);
        }
        float2 o;
        o.x = a0 + a1;
        o.y = b0 + b1;
        *reinterpret_cast<float2*>(orow + (size_t)r * kK) = o;
    }
}

// ---------------------------------------------------------------------------
// Fallback: round-1 fused kernel (proven correct) if ws too small.
// ---------------------------------------------------------------------------
__global__ __launch_bounds__(256, 2)
void gated_encoder_fused(const float* __restrict__ x,
                         const float* __restrict__ Wx,
                         const float* __restrict__ Wy,
                         const float* __restrict__ Wz,
                         float* __restrict__ out)
{
    __shared__ float t2[64][kF + 4];

    const int tid  = threadIdx.x;
    const int lane = tid & 63;
    const int wv   = tid >> 6;

    const int rloc = wv * 16 + (lane >> 2);
    const int row  = blockIdx.x * 64 + rloc;
    const int fg8  = (lane & 3) * 8;

    const float* __restrict__ xrow = x + (size_t)row * kJ;

    float acc[8];
#pragma unroll
    for (int u = 0; u < 8; ++u) acc[u] = 0.0f;

    for (int j = 0; j < kJ; j += 8) {
        const float4 xv0 = *reinterpret_cast<const float4*>(xrow + j);
        const float4 xv1 = *reinterpret_cast<const float4*>(xrow + j + 4);
        const float xs[8] = {xv0.x, xv0.y, xv0.z, xv0.w,
                             xv1.x, xv1.y, xv1.z, xv1.w};
#pragma unroll
        for (int u = 0; u < 8; ++u) {
            const float* wyp = Wy + (size_t)(j + u) * kF + fg8;
            const float4 w0 = *reinterpret_cast<const float4*>(wyp);
            const float4 w1 = *reinterpret_cast<const float4*>(wyp + 4);
            acc[0] = fmaf(xs[u], w0.x, acc[0]);
            acc[1] = fmaf(xs[u], w0.y, acc[1]);
            acc[2] = fmaf(xs[u], w0.z, acc[2]);
            acc[3] = fmaf(xs[u], w0.w, acc[3]);
            acc[4] = fmaf(xs[u], w1.x, acc[4]);
            acc[5] = fmaf(xs[u], w1.y, acc[5]);
            acc[6] = fmaf(xs[u], w1.z, acc[6]);
            acc[7] = fmaf(xs[u], w1.w, acc[7]);
        }
    }

    const int i = row & (kI - 1);
    const float* wxp = Wx + (size_t)i * kF + fg8;
    const float4 g0 = *reinterpret_cast<const float4*>(wxp);
    const float4 g1 = *reinterpret_cast<const float4*>(wxp + 4);
    float4 r0, r1;
    r0.x = acc[0] * g0.x;  r0.y = acc[1] * g0.y;
    r0.z = acc[2] * g0.z;  r0.w = acc[3] * g0.w;
    r1.x = acc[4] * g1.x;  r1.y = acc[5] * g1.y;
    r1.z = acc[6] * g1.z;  r1.w = acc[7] * g1.w;
    *reinterpret_cast<float4*>(&t2[rloc][fg8])     = r0;
    *reinterpret_cast<float4*>(&t2[rloc][fg8 + 4]) = r1;

    __syncthreads();

    const size_t outBase = (size_t)blockIdx.x * 64 * kK;

#pragma unroll
    for (int pass = 0; pass < 2; ++pass) {
        const int k1 = pass * 512 + tid;
        const int k2 = k1 + 256;
        const float* wz1 = Wz + (size_t)k1 * kF;
        const float* wz2 = Wz + (size_t)k2 * kF;
        float4 z1[8], z2[8];
#pragma unroll
        for (int m = 0; m < 8; ++m) {
            z1[m] = *reinterpret_cast<const float4*>(wz1 + 4 * m);
            z2[m] = *reinterpret_cast<const float4*>(wz2 + 4 * m);
        }
        for (int r = 0; r < 64; ++r) {
            float4 a1 = {0.f, 0.f, 0.f, 0.f};
            float4 a2 = {0.f, 0.f, 0.f, 0.f};
#pragma unroll
            for (int m = 0; m < 8; ++m) {
                const float4 tv = *reinterpret_cast<const float4*>(&t2[r][4 * m]);
                a1.x = fmaf(tv.x, z1[m].x, a1.x);
                a1.y = fmaf(tv.y, z1[m].y, a1.y);
                a1.z = fmaf(tv.z, z1[m].z, a1.z);
                a1.w = fmaf(tv.w, z1[m].w, a1.w);
                a2.x = fmaf(tv.x, z2[m].x, a2.x);
                a2.y = fmaf(tv.y, z2[m].y, a2.y);
                a2.z = fmaf(tv.z, z2[m].z, a2.z);
                a2.w = fmaf(tv.w, z2[m].w, a2.w);
            }
            out[outBase + (size_t)r * kK + k1] = (a1.x + a1.y) + (a1.z + a1.w);
            out[outBase + (size_t)r * kK + k2] = (a2.x + a2.y) + (a2.z + a2.w);
        }
    }
}

extern "C" void kernel_launch(void* const* d_in, const int* in_sizes, int n_in,
                              void* d_out, int out_size, void* d_ws, size_t ws_size,
                              hipStream_t stream) {
    const float* x  = (const float*)d_in[0];   // (B, I, J)
    const float* Wx = (const float*)d_in[1];   // (I, F)
    const float* Wy = (const float*)d_in[2];   // (J, F)
    const float* Wz = (const float*)d_in[3];   // (K, F)
    float* out = (float*)d_out;                // (B, I, K) f32

    const size_t tBytes = (size_t)kRows * kF * sizeof(float);   // 4 MiB

    if (ws_size >= tBytes && d_ws != nullptr) {
        float* t = (float*)d_ws;
        ge_stage1<<<dim3(kRows / 64), 512, 0, stream>>>(x, Wx, Wy, t);
        ge_stage2<<<dim3(kRows / 64), 512, 0, stream>>>(t, Wz, out);
    } else {
        gated_encoder_fused<<<dim3(kRows / 64), 256, 0, stream>>>(x, Wx, Wy, Wz, out);
    }
}

// Round 6
// 102.439 us; speedup vs baseline: 4.3668x; 1.0231x over previous
//
#include <hip/hip_runtime.h>

// GatedEncoderLayer: B=16, I=2048, J=1024, K=1024, F=32
// out[row,k] = sum_f [ (sum_j x[row,j]*Wy[j,f]) * Wx[row%I,f] ] * Wz[k,f]
constexpr int kI = 2048;
constexpr int kJ = 1024;
constexpr int kK = 1024;
constexpr int kF = 32;
constexpr int kRows = 16 * 2048;        // 32768

// ---------------------------------------------------------------------------
// Stage 1: t[row,f] = (sum_j x[row,j]*Wy[j,f]) * Wx[row%I,f]
// Round-5 was LDS-throughput-bound: 1 ds_read_b128 per 4 FMA (R=1).
// Now R=4 rows/thread: 1 ds_read feeds 16 FMA -> LDS instrs /4 (82->20 us).
// thread = (row-quad q:16, f-quad fq:8, j-half jh:2) = 256 thr; 64 rows/block;
// 512 blocks. Wy staged in paired 16KB chunks (one per j-half) = 32KB + 8.5KB
// reduce buffer -> 3 blocks/CU. Intra-wave dedup: x addr depends on (q,jh)
// -> 8 lines x 8-bcast; wy addr depends on fq -> 8 lines, 32 banks once.
// ---------------------------------------------------------------------------
constexpr int kCJ = 128;                // j per chunk per half

__global__ __launch_bounds__(256, 3)
void ge_stage1(const float* __restrict__ x,
               const float* __restrict__ Wx,
               const float* __restrict__ Wy,
               float* __restrict__ t)
{
    __shared__ float wyb[2][kCJ][kF];   // 32 KiB
    __shared__ float red[128][17];      // 8.5 KiB, padded stride 17

    const int tid = threadIdx.x;
    const int fq  = tid & 7;            // f-quad
    const int q   = (tid >> 3) & 15;    // row-quad
    const int jh  = tid >> 7;           // j-half
    const int f0  = fq * 4;
    const int rowBase = blockIdx.x * 64 + q * 4;

    const float* __restrict__ xr0 = x + (size_t)(rowBase + 0) * kJ + jh * 512;
    const float* __restrict__ xr1 = x + (size_t)(rowBase + 1) * kJ + jh * 512;
    const float* __restrict__ xr2 = x + (size_t)(rowBase + 2) * kJ + jh * 512;
    const float* __restrict__ xr3 = x + (size_t)(rowBase + 3) * kJ + jh * 512;

    float4 a0 = make_float4(0.f, 0.f, 0.f, 0.f);
    float4 a1 = make_float4(0.f, 0.f, 0.f, 0.f);
    float4 a2 = make_float4(0.f, 0.f, 0.f, 0.f);
    float4 a3 = make_float4(0.f, 0.f, 0.f, 0.f);

    for (int c = 0; c < 4; ++c) {
        __syncthreads();                // protect previous chunk's readers
        // stage both halves: threads 0-127 stage h=0, 128-255 h=1.
        // per half: 128 j x 32 f = 1024 float4 / 128 thr = 8 each, coalesced.
        {
            const int h  = tid >> 7;
            const int lt = tid & 127;
            const float4* src = reinterpret_cast<const float4*>(
                Wy + (size_t)(h * 512 + c * kCJ) * kF);
            float4* dst = reinterpret_cast<float4*>(&wyb[h][0][0]);
#pragma unroll
            for (int p = 0; p < 8; ++p)
                dst[lt + p * 128] = src[lt + p * 128];
        }
        __syncthreads();

        const int jc = c * kCJ;
#pragma unroll 2
        for (int jj = 0; jj < kCJ; jj += 4) {
            const float4 xv0 = *reinterpret_cast<const float4*>(xr0 + jc + jj);
            const float4 xv1 = *reinterpret_cast<const float4*>(xr1 + jc + jj);
            const float4 xv2 = *reinterpret_cast<const float4*>(xr2 + jc + jj);
            const float4 xv3 = *reinterpret_cast<const float4*>(xr3 + jc + jj);
            const float xs0[4] = {xv0.x, xv0.y, xv0.z, xv0.w};
            const float xs1[4] = {xv1.x, xv1.y, xv1.z, xv1.w};
            const float xs2[4] = {xv2.x, xv2.y, xv2.z, xv2.w};
            const float xs3[4] = {xv3.x, xv3.y, xv3.z, xv3.w};
#pragma unroll
            for (int u = 0; u < 4; ++u) {
                const float4 w = *reinterpret_cast<const float4*>(&wyb[jh][jj + u][f0]);
                a0.x = fmaf(xs0[u], w.x, a0.x);
                a0.y = fmaf(xs0[u], w.y, a0.y);
                a0.z = fmaf(xs0[u], w.z, a0.z);
                a0.w = fmaf(xs0[u], w.w, a0.w);
                a1.x = fmaf(xs1[u], w.x, a1.x);
                a1.y = fmaf(xs1[u], w.y, a1.y);
                a1.z = fmaf(xs1[u], w.z, a1.z);
                a1.w = fmaf(xs1[u], w.w, a1.w);
                a2.x = fmaf(xs2[u], w.x, a2.x);
                a2.y = fmaf(xs2[u], w.y, a2.y);
                a2.z = fmaf(xs2[u], w.z, a2.z);
                a2.w = fmaf(xs2[u], w.w, a2.w);
                a3.x = fmaf(xs3[u], w.x, a3.x);
                a3.y = fmaf(xs3[u], w.y, a3.y);
                a3.z = fmaf(xs3[u], w.z, a3.z);
                a3.w = fmaf(xs3[u], w.w, a3.w);
            }
        }
    }

    // combine the two j-halves: jh=1 threads publish, jh=0 threads finish.
    __syncthreads();                    // wyb no longer needed
    if (jh == 1) {
        const int lt = tid & 127;
        float* rp = &red[lt][0];
        rp[0]  = a0.x; rp[1]  = a0.y; rp[2]  = a0.z; rp[3]  = a0.w;
        rp[4]  = a1.x; rp[5]  = a1.y; rp[6]  = a1.z; rp[7]  = a1.w;
        rp[8]  = a2.x; rp[9]  = a2.y; rp[10] = a2.z; rp[11] = a2.w;
        rp[12] = a3.x; rp[13] = a3.y; rp[14] = a3.z; rp[15] = a3.w;
    }
    __syncthreads();
    if (jh == 0) {
        const float* rp = &red[tid][0];
        a0.x += rp[0];  a0.y += rp[1];  a0.z += rp[2];  a0.w += rp[3];
        a1.x += rp[4];  a1.y += rp[5];  a1.z += rp[6];  a1.w += rp[7];
        a2.x += rp[8];  a2.y += rp[9];  a2.z += rp[10]; a2.w += rp[11];
        a3.x += rp[12]; a3.y += rp[13]; a3.z += rp[14]; a3.w += rp[15];

        float4 outv[4] = {a0, a1, a2, a3};
#pragma unroll
        for (int rr = 0; rr < 4; ++rr) {
            const int row = rowBase + rr;
            const int i   = row & (kI - 1);
            const float4 g = *reinterpret_cast<const float4*>(
                Wx + (size_t)i * kF + f0);
            float4 v = outv[rr];
            v.x *= g.x; v.y *= g.y; v.z *= g.z; v.w *= g.w;
            *reinterpret_cast<float4*>(t + (size_t)row * kF + f0) = v;
        }
    }
}

// ---------------------------------------------------------------------------
// Stage 2: out[row,k] = sum_f t[row,f] * Wz[k,f]   (~28 us measured, round 5)
// 512 blocks x 512 threads, 64 rows/block, thread owns 2 k-columns with Wz
// in 64 VGPRs. launch_bounds(512,2): the (512,4) variant spilled (round 4).
// ---------------------------------------------------------------------------
__global__ __launch_bounds__(512, 2)
void ge_stage2(const float* __restrict__ t,
               const float* __restrict__ Wz,
               float* __restrict__ out)
{
    __shared__ float t2[64][kF];                       // 8 KiB = 512 float4

    const int tid = threadIdx.x;
    const int rowBase = blockIdx.x * 64;

    reinterpret_cast<float4*>(&t2[0][0])[tid] =
        reinterpret_cast<const float4*>(t + (size_t)rowBase * kF)[tid];

    const int k0 = tid * 2;
    float4 wa[8], wb[8];
#pragma unroll
    for (int q = 0; q < 8; ++q) {
        wa[q] = *reinterpret_cast<const float4*>(Wz + (size_t)k0 * kF + q * 4);
        wb[q] = *reinterpret_cast<const float4*>(Wz + (size_t)(k0 + 1) * kF + q * 4);
    }
    __syncthreads();

    float* __restrict__ orow = out + (size_t)rowBase * kK + k0;

    for (int r = 0; r < 64; ++r) {
        float4 tr[8];
#pragma unroll
        for (int q = 0; q < 8; ++q)
            tr[q] = *reinterpret_cast<const float4*>(&t2[r][q * 4]);

        float a0 = 0.f, a1 = 0.f, b0 = 0.f, b1 = 0.f;
#pragma unroll
        for (int q = 0; q < 8; q += 2) {
            a0 = fmaf(tr[q].x, wa[q].x, a0);
            a0 = fmaf(tr[q].y, wa[q].y, a0);
            a0 = fmaf(tr[q].z, wa[q].z, a0);
            a0 = fmaf(tr[q].w, wa[q].w, a0);
            a1 = fmaf(tr[q + 1].x, wa[q + 1].x, a1);
            a1 = fmaf(tr[q + 1].y, wa[q + 1].y, a1);
            a1 = fmaf(tr[q + 1].z, wa[q + 1].z, a1);
            a1 = fmaf(tr[q + 1].w, wa[q + 1].w, a1);
            b0 = fmaf(tr[q].x, wb[q].x, b0);
            b0 = fmaf(tr[q].y, wb[q].y, b0);
            b0 = fmaf(tr[q].z, wb[q].z, b0);
            b0 = fmaf(tr[q].w, wb[q].w, b0);
            b1 = fmaf(tr[q + 1].x, wb[q + 1].x, b1);
            b1 = fmaf(tr[q + 1].y, wb[q + 1].y, b1);
            b1 = fmaf(tr[q + 1].z, wb[q + 1].z, b1);
            b1 = fmaf(tr[q + 1].w, wb[q + 1].w, b1);
        }
        float2 o;
        o.x = a0 + a1;
        o.y = b0 + b1;
        *reinterpret_cast<float2*>(orow + (size_t)r * kK) = o;
    }
}

// ---------------------------------------------------------------------------
// Fallback: round-1 fused kernel (proven correct) if ws too small.
// ---------------------------------------------------------------------------
__global__ __launch_bounds__(256, 2)
void gated_encoder_fused(const float* __restrict__ x,
                         const float* __restrict__ Wx,
                         const float* __restrict__ Wy,
                         const float* __restrict__ Wz,
                         float* __restrict__ out)
{
    __shared__ float t2[64][kF + 4];

    const int tid  = threadIdx.x;
    const int lane = tid & 63;
    const int wv   = tid >> 6;

    const int rloc = wv * 16 + (lane >> 2);
    const int row  = blockIdx.x * 64 + rloc;
    const int fg8  = (lane & 3) * 8;

    const float* __restrict__ xrow = x + (size_t)row * kJ;

    float acc[8];
#pragma unroll
    for (int u = 0; u < 8; ++u) acc[u] = 0.0f;

    for (int j = 0; j < kJ; j += 8) {
        const float4 xv0 = *reinterpret_cast<const float4*>(xrow + j);
        const float4 xv1 = *reinterpret_cast<const float4*>(xrow + j + 4);
        const float xs[8] = {xv0.x, xv0.y, xv0.z, xv0.w,
                             xv1.x, xv1.y, xv1.z, xv1.w};
#pragma unroll
        for (int u = 0; u < 8; ++u) {
            const float* wyp = Wy + (size_t)(j + u) * kF + fg8;
            const float4 w0 = *reinterpret_cast<const float4*>(wyp);
            const float4 w1 = *reinterpret_cast<const float4*>(wyp + 4);
            acc[0] = fmaf(xs[u], w0.x, acc[0]);
            acc[1] = fmaf(xs[u], w0.y, acc[1]);
            acc[2] = fmaf(xs[u], w0.z, acc[2]);
            acc[3] = fmaf(xs[u], w0.w, acc[3]);
            acc[4] = fmaf(xs[u], w1.x, acc[4]);
            acc[5] = fmaf(xs[u], w1.y, acc[5]);
            acc[6] = fmaf(xs[u], w1.z, acc[6]);
            acc[7] = fmaf(xs[u], w1.w, acc[7]);
        }
    }

    const int i = row & (kI - 1);
    const float* wxp = Wx + (size_t)i * kF + fg8;
    const float4 g0 = *reinterpret_cast<const float4*>(wxp);
    const float4 g1 = *reinterpret_cast<const float4*>(wxp + 4);
    float4 r0, r1;
    r0.x = acc[0] * g0.x;  r0.y = acc[1] * g0.y;
    r0.z = acc[2] * g0.z;  r0.w = acc[3] * g0.w;
    r1.x = acc[4] * g1.x;  r1.y = acc[5] * g1.y;
    r1.z = acc[6] * g1.z;  r1.w = acc[7] * g1.w;
    *reinterpret_cast<float4*>(&t2[rloc][fg8])     = r0;
    *reinterpret_cast<float4*>(&t2[rloc][fg8 + 4]) = r1;

    __syncthreads();

    const size_t outBase = (size_t)blockIdx.x * 64 * kK;

#pragma unroll
    for (int pass = 0; pass < 2; ++pass) {
        const int k1 = pass * 512 + tid;
        const int k2 = k1 + 256;
        const float* wz1 = Wz + (size_t)k1 * kF;
        const float* wz2 = Wz + (size_t)k2 * kF;
        float4 z1[8], z2[8];
#pragma unroll
        for (int m = 0; m < 8; ++m) {
            z1[m] = *reinterpret_cast<const float4*>(wz1 + 4 * m);
            z2[m] = *reinterpret_cast<const float4*>(wz2 + 4 * m);
        }
        for (int r = 0; r < 64; ++r) {
            float4 a1 = {0.f, 0.f, 0.f, 0.f};
            float4 a2 = {0.f, 0.f, 0.f, 0.f};
#pragma unroll
            for (int m = 0; m < 8; ++m) {
                const float4 tv = *reinterpret_cast<const float4*>(&t2[r][4 * m]);
                a1.x = fmaf(tv.x, z1[m].x, a1.x);
                a1.y = fmaf(tv.y, z1[m].y, a1.y);
                a1.z = fmaf(tv.z, z1[m].z, a1.z);
                a1.w = fmaf(tv.w, z1[m].w, a1.w);
                a2.x = fmaf(tv.x, z2[m].x, a2.x);
                a2.y = fmaf(tv.y, z2[m].y, a2.y);
                a2.z = fmaf(tv.z, z2[m].z, a2.z);
                a2.w = fmaf(tv.w, z2[m].w, a2.w);
            }
            out[outBase + (size_t)r * kK + k1] = (a1.x + a1.y) + (a1.z + a1.w);
            out[outBase + (size_t)r * kK + k2] = (a2.x + a2.y) + (a2.z + a2.w);
        }
    }
}

extern "C" void kernel_launch(void* const* d_in, const int* in_sizes, int n_in,
                              void* d_out, int out_size, void* d_ws, size_t ws_size,
                              hipStream_t stream) {
    const float* x  = (const float*)d_in[0];   // (B, I, J)
    const float* Wx = (const float*)d_in[1];   // (I, F)
    const float* Wy = (const float*)d_in[2];   // (J, F)
    const float* Wz = (const float*)d_in[3];   // (K, F)
    float* out = (float*)d_out;                // (B, I, K) f32

    const size_t tBytes = (size_t)kRows * kF * sizeof(float);   // 4 MiB

    if (ws_size >= tBytes && d_ws != nullptr) {
        float* t = (float*)d_ws;
        ge_stage1<<<dim3(kRows / 64), 256, 0, stream>>>(x, Wx, Wy, t);
        ge_stage2<<<dim3(kRows / 64), 512, 0, stream>>>(t, Wz, out);
    } else {
        gated_encoder_fused<<<dim3(kRows / 64), 256, 0, stream>>>(x, Wx, Wy, Wz, out);
    }
}